// Round 15
// baseline (805.658 us; speedup 1.0000x reference)
//
#include <hip/hip_runtime.h>
#include <hip/hip_bf16.h>

#define NN 20000
#define NE 600000
#define DIN 128
#define DD 64
#define HH 4
#define DKK 16
#define LL 4
#define TT 3
#define RR 32
#define RP_TPW 10                 // tiles (16 nodes) per wave in relpreQV
#define RP_CH  125                // chunks per r: 125*10*16 = 20000

typedef __attribute__((ext_vector_type(8))) short bf16x8;
typedef __attribute__((ext_vector_type(4))) float f32x4;

__device__ __forceinline__ int src_nt(int e) { return e <= 9 ? 0 : (e <= 21 ? 1 : 2); }
__device__ __forceinline__ int dst_nt(int e) {
    if (e <= 2 || (e >= 10 && e <= 13) || (e >= 22 && e <= 24)) return 0;
    if ((e >= 3 && e <= 6) || (e >= 14 && e <= 17) || (e >= 25 && e <= 28)) return 1;
    return 2;
}
__device__ __forceinline__ float bf_lo(unsigned u) { return __uint_as_float(u << 16); }
__device__ __forceinline__ float bf_hi(unsigned u) { return __uint_as_float(u & 0xffff0000u); }
// round-to-nearest-even f32 -> bf16 bits
__device__ __forceinline__ ushort f2bf(float x) {
    unsigned u = __float_as_uint(x);
    return (ushort)((u + 0x7fffu + ((u >> 16) & 1u)) >> 16);
}

// ---- stable type-sort permutation: perm[slot]=orig, iperm[orig]=slot, ptype[slot] ----
__global__ void perm_scan_kernel(const int* __restrict__ ntype, int* __restrict__ perm,
                                 int* __restrict__ iperm, int* __restrict__ ptype) {
    __shared__ int wsum3[3][16];
    __shared__ int carry[3];
    __shared__ int offs[3];
    int tid = threadIdx.x;            // blockDim = 1024
    int lane = tid & 63, wid = tid >> 6;
    int loc[3] = {0, 0, 0};
    for (int i = tid; i < NN; i += 1024) loc[ntype[i]]++;
#pragma unroll
    for (int t = 0; t < 3; ++t) {
        int v = loc[t];
#pragma unroll
        for (int off = 1; off < 64; off <<= 1) v += __shfl_xor(v, off);
        if (lane == 0) wsum3[t][wid] = v;
    }
    __syncthreads();
    if (tid == 0) {
        int c0 = 0, c1 = 0;
        for (int i = 0; i < 16; ++i) { c0 += wsum3[0][i]; c1 += wsum3[1][i]; }
        offs[0] = 0; offs[1] = c0; offs[2] = c0 + c1;
        carry[0] = 0; carry[1] = 0; carry[2] = 0;
    }
    __syncthreads();
    for (int base = 0; base < NN; base += 1024) {
        int i = base + tid;
        int t = (i < NN) ? ntype[i] : -1;
        int exc[3];
#pragma unroll
        for (int tt = 0; tt < 3; ++tt) {
            int v = (t == tt) ? 1 : 0;
            int x = v;
#pragma unroll
            for (int off = 1; off < 64; off <<= 1) {
                int y = __shfl_up(x, off);
                if (lane >= off) x += y;
            }
            if (lane == 63) wsum3[tt][wid] = x;
            exc[tt] = x - v;
        }
        __syncthreads();
        if (wid == 0 && lane < 16) {
#pragma unroll
            for (int tt = 0; tt < 3; ++tt) {
                int w = wsum3[tt][lane];
#pragma unroll
                for (int off = 1; off < 16; off <<= 1) {
                    int y = __shfl_up(w, off);
                    if (lane >= off) w += y;
                }
                wsum3[tt][lane] = w;
            }
        }
        __syncthreads();
        if (i < NN) {
            int woff = (wid > 0) ? wsum3[t][wid - 1] : 0;
            int slot = offs[t] + carry[t] + woff + exc[t];
            perm[slot] = i; iperm[i] = slot; ptype[slot] = t;
        }
        __syncthreads();
        if (tid == 0) { for (int tt = 0; tt < 3; ++tt) carry[tt] += wsum3[tt][15]; }
        __syncthreads();
    }
}

// ---- x = tanh(h @ adapt_W[ntype] + adapt_b[ntype]); bf16 out, permuted ----
__global__ void adapt_kernel(const float* __restrict__ h, const int* __restrict__ ntype,
                             const int* __restrict__ iperm,
                             const float* __restrict__ W, const float* __restrict__ b,
                             ushort* __restrict__ xbf) {
    int wid = (blockIdx.x * blockDim.x + threadIdx.x) >> 6;
    int lane = threadIdx.x & 63;
    if (wid >= NN) return;
    int t = ntype[wid];
    const float* Wt = W + (size_t)t * DIN * DD;
    float h0 = h[(size_t)wid * DIN + lane];
    float h1 = h[(size_t)wid * DIN + 64 + lane];
    float acc = b[t * DD + lane];
#pragma unroll
    for (int d = 0; d < 64; ++d) acc += __shfl(h0, d) * Wt[d * DD + lane];
#pragma unroll
    for (int d = 0; d < 64; ++d) acc += __shfl(h1, d) * Wt[(64 + d) * DD + lane];
    xbf[(size_t)iperm[wid] * DD + lane] = f2bf(tanhf(acc));
}

// ---- CSR build over PERMUTED dst; fill writes ONE packed int4 per edge ----
__global__ void csr_count_kernel(const int* __restrict__ dst, const int* __restrict__ iperm,
                                 int* __restrict__ cnt) {
    int e = blockIdx.x * blockDim.x + threadIdx.x;
    if (e < NE) atomicAdd(&cnt[iperm[dst[e]]], 1);
}

// ---- presence bitmaps over PERMUTED ids: inm[iperm[dst]] |= 1<<r ; outm[iperm[src]] ----
__global__ void mask_build_kernel(const int* __restrict__ src, const int* __restrict__ dst,
                                  const int* __restrict__ et, const int* __restrict__ iperm,
                                  unsigned* __restrict__ inm, unsigned* __restrict__ outm) {
    int e = blockIdx.x * blockDim.x + threadIdx.x;
    if (e >= NE) return;
    unsigned bit = 1u << et[e];
    atomicOr(&inm[iperm[dst[e]]], bit);
    atomicOr(&outm[iperm[src[e]]], bit);
}

__global__ void csr_scan_kernel(const int* __restrict__ cnt, int* __restrict__ rowptr,
                                int* __restrict__ cursor) {
    __shared__ int wsuml[16];
    __shared__ int s_carry;
    int tid = threadIdx.x;            // blockDim = 1024
    int lane = tid & 63, wid = tid >> 6;
    if (tid == 0) s_carry = 0;
    __syncthreads();
    for (int base = 0; base < NN; base += 1024) {
        int i = base + tid;
        int v = (i < NN) ? cnt[i] : 0;
        int x = v;
#pragma unroll
        for (int off = 1; off < 64; off <<= 1) {
            int y = __shfl_up(x, off);
            if (lane >= off) x += y;
        }
        if (lane == 63) wsuml[wid] = x;
        __syncthreads();
        if (wid == 0 && lane < 16) {
            int w = wsuml[lane];
#pragma unroll
            for (int off = 1; off < 16; off <<= 1) {
                int y = __shfl_up(w, off);
                if (lane >= off) w += y;
            }
            wsuml[lane] = w;
        }
        __syncthreads();
        int woff = (wid > 0) ? wsuml[wid - 1] : 0;
        int carry = s_carry;
        int excl = carry + woff + x - v;
        if (i < NN) { rowptr[i] = excl; cursor[i] = excl; }
        __syncthreads();
        if (tid == 1023) s_carry = carry + wsuml[15];
        __syncthreads();
    }
    if (tid == 0) rowptr[NN] = NE;
}

__global__ void csr_fill_kernel(const int* __restrict__ src, const int* __restrict__ dst,
                                const int* __restrict__ et, const int* __restrict__ iperm,
                                int* __restrict__ cursor, int4* __restrict__ edges) {
    int e = blockIdx.x * blockDim.x + threadIdx.x;
    if (e >= NE) return;
    int d = iperm[dst[e]];
    int p = atomicAdd(&cursor[d], 1);
    edges[p] = make_int4(iperm[src[e]], d, et[e], 0);
}

// ---- kqv via MFMA over type-sorted nodes; block = 16 nodes, wave = head o-tile ----
__global__ __launch_bounds__(256) void kqv_mfma_kernel(
        const ushort* __restrict__ xbf, const int* __restrict__ ptype,
        const float* __restrict__ Wk, const float* __restrict__ bk,
        const float* __restrict__ Wq, const float* __restrict__ bq,
        const float* __restrict__ Wv, const float* __restrict__ bv,
        const float* __restrict__ afc,
        ushort* __restrict__ kbf, ushort* __restrict__ qbf, ushort* __restrict__ vbf,
        float* __restrict__ na_q, float* __restrict__ na_k) {
    int p0 = blockIdx.x * 16;
    int lane = threadIdx.x & 63;
    int w = threadIdx.x >> 6;       // head / o-tile
    int m = lane & 15, g = lane >> 4;
    int k0 = g * 8, frow = g * 4, ob = w * 16;
    int myn = p0 + m;
    int myt = ptype[myn];
    int t0 = ptype[p0], t1 = ptype[p0 + 15];
    bf16x8 b0 = *(const bf16x8*)(xbf + (size_t)myn * DD + k0);
    bf16x8 b1 = *(const bf16x8*)(xbf + (size_t)myn * DD + 32 + k0);
    for (int t = t0; t <= t1; ++t) {
        const float* WkT = Wk + (size_t)t * DD * DD; const float* bkT = bk + t * DD;
        const float* WqT = Wq + (size_t)t * DD * DD; const float* bqT = bq + t * DD;
        const float* WvT = Wv + (size_t)t * DD * DD; const float* bvT = bv + t * DD;
        bf16x8 ak0, ak1, aq0, aq1, av0, av1;
        int col = ob + m;
#pragma unroll
        for (int j = 0; j < 8; ++j) {
            ak0[j] = (short)f2bf(WkT[(k0 + j) * DD + col]);
            ak1[j] = (short)f2bf(WkT[(32 + k0 + j) * DD + col]);
            aq0[j] = (short)f2bf(WqT[(k0 + j) * DD + col]);
            aq1[j] = (short)f2bf(WqT[(32 + k0 + j) * DD + col]);
            av0[j] = (short)f2bf(WvT[(k0 + j) * DD + col]);
            av1[j] = (short)f2bf(WvT[(32 + k0 + j) * DD + col]);
        }
        f32x4 z = {0.f, 0.f, 0.f, 0.f};
        f32x4 ck = __builtin_amdgcn_mfma_f32_16x16x32_bf16(ak0, b0, z, 0, 0, 0);
        ck = __builtin_amdgcn_mfma_f32_16x16x32_bf16(ak1, b1, ck, 0, 0, 0);
        f32x4 cq = __builtin_amdgcn_mfma_f32_16x16x32_bf16(aq0, b0, z, 0, 0, 0);
        cq = __builtin_amdgcn_mfma_f32_16x16x32_bf16(aq1, b1, cq, 0, 0, 0);
        f32x4 cv = __builtin_amdgcn_mfma_f32_16x16x32_bf16(av0, b0, z, 0, 0, 0);
        cv = __builtin_amdgcn_mfma_f32_16x16x32_bf16(av1, b1, cv, 0, 0, 0);
        float sq = 0.f, sk = 0.f;
        ushort4 okk, oqq, ovv;
#pragma unroll
        for (int j = 0; j < 4; ++j) {
            int o = ob + frow + j;
            float kk = ck[j] + bkT[o];
            float qq = cq[j] + bqT[o];
            float vv = cv[j] + bvT[o];
            sq += qq * afc[frow + j];
            sk += kk * afc[16 + frow + j];
            ((ushort*)&okk)[j] = f2bf(kk);
            ((ushort*)&oqq)[j] = f2bf(qq);
            ((ushort*)&ovv)[j] = f2bf(vv);
        }
        sq += __shfl_xor(sq, 16); sq += __shfl_xor(sq, 32);
        sk += __shfl_xor(sk, 16); sk += __shfl_xor(sk, 32);
        if (myt == t) {
            size_t ob8 = (size_t)myn * DD + ob + frow;
            *(ushort4*)(kbf + ob8) = okk;
            *(ushort4*)(qbf + ob8) = oqq;
            *(ushort4*)(vbf + ob8) = ovv;
            if (g == 0) {
                na_q[myn * HH + w] = sq;
                na_k[myn * HH + w] = sk;
            }
        }
    }
}

// ---- relpre QV: qr[n,r] = A_r q[n], vr[n,r] = M_r^T v[n]. MFMA + swizzled LDS
//      transpose + presence-masked full-row stores ----
__global__ __launch_bounds__(256) void relpreQV_kernel(
        const ushort* __restrict__ qbf, const ushort* __restrict__ vbf,
        const float* __restrict__ relA, const float* __restrict__ relM,
        const unsigned* __restrict__ inmask, const unsigned* __restrict__ outmask,
        ushort* __restrict__ qr, ushort* __restrict__ vr) {
    __shared__ __align__(16) ushort lds[4][2][16 * DD];   // [wave][Q/V][16 rows x 128B]
    int gw = (blockIdx.x * blockDim.x + threadIdx.x) >> 6;
    int lane = threadIdx.x & 63;
    int wv = threadIdx.x >> 6;
    int r = gw / RP_CH;
    int c = gw % RP_CH;
    int m = lane & 15;
    int g = lane >> 4;
    int k0 = g * 8;
    bf16x8 aQ[HH], aV[HH];
#pragma unroll
    for (int h = 0; h < HH; ++h) {
        bf16x8 zq = {0, 0, 0, 0, 0, 0, 0, 0};
        bf16x8 zv = {0, 0, 0, 0, 0, 0, 0, 0};
        if (k0 < 16) {
            const float* Ab = relA + (size_t)(r * HH + h) * 256;
            const float* Mb = relM + (size_t)(r * HH + h) * 256;
#pragma unroll
            for (int j = 0; j < 8; ++j) {
                zq[j] = (short)f2bf(Ab[m * 16 + k0 + j]);
                zv[j] = (short)f2bf(Mb[(k0 + j) * 16 + m]);
            }
        }
        aQ[h] = zq; aV[h] = zv;
    }
    int ksafe = k0 & 8;
    int nd = lane >> 3;           // store phase: node sub-index 0..7
    int ch = lane & 7;            // 16B chunk within node row
    int wswz = (m & 7) << 1;      // write-side chunk XOR
    for (int t = 0; t < RP_TPW; ++t) {
        int n0 = (c * RP_TPW + t) * 16;
#pragma unroll
        for (int h = 0; h < HH; ++h) {
            size_t brow = (size_t)(n0 + m) * DD + h * 16 + ksafe;
            bf16x8 bQ = *(const bf16x8*)(qbf + brow);
            bf16x8 bV = *(const bf16x8*)(vbf + brow);
            f32x4 z = {0.f, 0.f, 0.f, 0.f};
            f32x4 cq = __builtin_amdgcn_mfma_f32_16x16x32_bf16(aQ[h], bQ, z, 0, 0, 0);
            f32x4 cv = __builtin_amdgcn_mfma_f32_16x16x32_bf16(aV[h], bV, z, 0, 0, 0);
            ushort4 oq, ov;
            oq.x = f2bf(cq[0]); oq.y = f2bf(cq[1]); oq.z = f2bf(cq[2]); oq.w = f2bf(cq[3]);
            ov.x = f2bf(cv[0]); ov.y = f2bf(cv[1]); ov.z = f2bf(cv[2]); ov.w = f2bf(cv[3]);
            int cidx = (h * 4 + g) ^ wswz;         // swizzled 8B-chunk index
            int li = m * DD + cidx * 4;
            *(ushort4*)&lds[wv][0][li] = oq;
            *(ushort4*)&lds[wv][1][li] = ov;
        }
        asm volatile("s_waitcnt lgkmcnt(0)" ::: "memory");
#pragma unroll
        for (int p = 0; p < 2; ++p) {
            int node = p * 8 + nd;
            unsigned im = inmask[n0 + node];
            unsigned om = outmask[n0 + node];
            int c0 = (ch * 2) ^ ((node & 7) << 1); // same XOR on read side
            int li = node * DD + c0 * 4;
            uint4 dq = *(const uint4*)&lds[wv][0][li];
            uint4 dv = *(const uint4*)&lds[wv][1][li];
            size_t gb = ((size_t)(n0 + node) * RR + r) * DD + ch * 8;
            if ((im >> r) & 1u) *(uint4*)(qr + gb) = dq;
            if ((om >> r) & 1u) *(uint4*)(vr + gb) = dv;
        }
        asm volatile("s_waitcnt lgkmcnt(0)" ::: "memory");
    }
}

// ---- edge pass: thread per (sorted-j, h); packed edge load ----
__global__ void edge_logitsB_kernel(const ushort* __restrict__ kbf,
                                    const ushort* __restrict__ qr,
                                    const int4* __restrict__ edges,
                                    const float* __restrict__ pri,
                                    const float* __restrict__ nta, const float* __restrict__ nta1,
                                    const float* __restrict__ na_q, const float* __restrict__ na_k,
                                    const float* __restrict__ wgt,
                                    float* __restrict__ ex_out, float* __restrict__ den) {
    int idx = blockIdx.x * blockDim.x + threadIdx.x;
    if (idx >= NE * HH) return;
    int j = idx >> 2, hh = idx & 3;
    int4 ed = edges[j];
    int s = ed.x, dd = ed.y, r = ed.z;
    const uint4* qp = (const uint4*)(qr + ((size_t)dd * RR + r) * DD + hh * 16);
    uint4 a0 = qp[0], a1 = qp[1];
    const uint4* kp = (const uint4*)(kbf + (size_t)s * DD + hh * 16);
    uint4 b0 = kp[0], b1 = kp[1];
    float att = bf_lo(a0.x) * bf_lo(b0.x) + bf_hi(a0.x) * bf_hi(b0.x)
              + bf_lo(a0.y) * bf_lo(b0.y) + bf_hi(a0.y) * bf_hi(b0.y)
              + bf_lo(a0.z) * bf_lo(b0.z) + bf_hi(a0.z) * bf_hi(b0.z)
              + bf_lo(a0.w) * bf_lo(b0.w) + bf_hi(a0.w) * bf_hi(b0.w)
              + bf_lo(a1.x) * bf_lo(b1.x) + bf_hi(a1.x) * bf_hi(b1.x)
              + bf_lo(a1.y) * bf_lo(b1.y) + bf_hi(a1.y) * bf_hi(b1.y)
              + bf_lo(a1.z) * bf_lo(b1.z) + bf_hi(a1.z) * bf_hi(b1.z)
              + bf_lo(a1.w) * bf_lo(b1.w) + bf_hi(a1.w) * bf_hi(b1.w);
    att = att * pri[r * HH + hh] * 0.25f;
    float c = nta1[dst_nt(r)] * na_q[dd * HH + hh] + nta[src_nt(r)] * na_k[s * HH + hh];
    float na = c > 0.f ? c : 0.01f * c;
    float sw = 1.f / (1.f + expf(-wgt[0]));
    float exv = expf(att + sw * na);
    ex_out[idx] = exv;
    atomicAdd(&den[((size_t)dd * RR + r) * HH + hh], exv);
}

// ---- accumulation: wave per dst; 4x-unrolled; packed edge loads ----
__global__ void accum_csr_kernel(const ushort* __restrict__ vr,
                                 const int4* __restrict__ edges,
                                 const int* __restrict__ rowptr,
                                 const float* __restrict__ ex, const float* __restrict__ den,
                                 float* __restrict__ tacc) {
    int n = (blockIdx.x * blockDim.x + threadIdx.x) >> 6;
    int lane = threadIdx.x & 63;
    if (n >= NN) return;
    int beg = rowptr[n], end = rowptr[n + 1];
    int hh = lane >> 4;
    const float* denrow = den + (size_t)n * RR * HH + hh;
    float acc = 0.f;
    int j = beg;
    for (; j + 3 < end; j += 4) {
        int4 e0i = edges[j], e1i = edges[j + 1], e2i = edges[j + 2], e3i = edges[j + 3];
        float v0 = bf_lo((unsigned)vr[((size_t)e0i.x * RR + e0i.z) * DD + lane]);
        float v1 = bf_lo((unsigned)vr[((size_t)e1i.x * RR + e1i.z) * DD + lane]);
        float v2 = bf_lo((unsigned)vr[((size_t)e2i.x * RR + e2i.z) * DD + lane]);
        float v3 = bf_lo((unsigned)vr[((size_t)e3i.x * RR + e3i.z) * DD + lane]);
        float e0 = ex[(size_t)(j)     * HH + hh];
        float e1 = ex[(size_t)(j + 1) * HH + hh];
        float e2 = ex[(size_t)(j + 2) * HH + hh];
        float e3 = ex[(size_t)(j + 3) * HH + hh];
        float d0 = denrow[e0i.z * HH];
        float d1 = denrow[e1i.z * HH];
        float d2 = denrow[e2i.z * HH];
        float d3 = denrow[e3i.z * HH];
        acc += e0 * __builtin_amdgcn_rcpf(d0) * v0;
        acc += e1 * __builtin_amdgcn_rcpf(d1) * v1;
        acc += e2 * __builtin_amdgcn_rcpf(d2) * v2;
        acc += e3 * __builtin_amdgcn_rcpf(d3) * v3;
    }
    for (; j < end; ++j) {
        int4 ei = edges[j];
        float val = bf_lo((unsigned)vr[((size_t)ei.x * RR + ei.z) * DD + lane]);
        float p = ex[(size_t)j * HH + hh] * __builtin_amdgcn_rcpf(denrow[ei.z * HH]);
        acc += p * val;
    }
    tacc[(size_t)n * DD + lane] = acc;
}

// ---- node finalize (permuted space; last layer un-permutes to d_out) ----
__global__ void node_out_kernel(const ushort* __restrict__ xbf_in, const float* __restrict__ tacc,
                                const float* __restrict__ den, const int* __restrict__ ptype,
                                const int* __restrict__ perm,
                                const float* __restrict__ Wa, const float* __restrict__ ba,
                                const float* __restrict__ skipp,
                                const float* __restrict__ ln_g, const float* __restrict__ ln_b,
                                ushort* __restrict__ xbf_out, float* __restrict__ fout, int last) {
    int n = (blockIdx.x * blockDim.x + threadIdx.x) >> 6;
    int lane = threadIdx.x & 63;
    if (n >= NN) return;
    int t = ptype[n];
    int pres = 0;
    if (lane < RR) pres = (den[((size_t)n * RR + lane) * HH] > 0.f) ? 1 : 0;
    unsigned long long mask = __ballot(pres != 0);
    float cnt = (float)__popcll(mask);
    float divisor = fmaxf(cnt, 1.0f);
    float tv = tacc[(size_t)n * DD + lane] / divisor;
    const float* Wt = Wa + (size_t)t * DD * DD;
    float acc = ba[t * DD + lane];
#pragma unroll
    for (int d = 0; d < 64; ++d) acc += __shfl(tv, d) * Wt[d * DD + lane];
    float alpha = 1.f / (1.f + expf(-skipp[t]));
    float xi = bf_lo((unsigned)xbf_in[(size_t)n * DD + lane]);
    float out = acc * alpha + xi * (1.f - alpha);
    float s = out;
#pragma unroll
    for (int off = 1; off < 64; off <<= 1) s += __shfl_xor(s, off);
    float mu = s * (1.f / 64.f);
    float d0 = out - mu;
    float s2 = d0 * d0;
#pragma unroll
    for (int off = 1; off < 64; off <<= 1) s2 += __shfl_xor(s2, off);
    float var = s2 * (1.f / 64.f);
    float xn = d0 * rsqrtf(var + 1e-5f);
    float res = xn * ln_g[t * DD + lane] + ln_b[t * DD + lane];
    if (last) fout[(size_t)perm[n] * DD + lane] = res;
    else      xbf_out[(size_t)n * DD + lane] = f2bf(res);
}

extern "C" void kernel_launch(void* const* d_in, const int* in_sizes, int n_in,
                              void* d_out, int out_size, void* d_ws, size_t ws_size,
                              hipStream_t stream) {
    const float* h       = (const float*)d_in[0];
    const int*   src     = (const int*)d_in[1];
    const int*   dst     = (const int*)d_in[2];
    const int*   etype   = (const int*)d_in[3];
    const int*   ntype   = (const int*)d_in[4];
    const float* adapt_W = (const float*)d_in[5];
    const float* adapt_b = (const float*)d_in[6];
    const float* Wk      = (const float*)d_in[7];
    const float* bk      = (const float*)d_in[8];
    const float* Wq      = (const float*)d_in[9];
    const float* bq      = (const float*)d_in[10];
    const float* Wv      = (const float*)d_in[11];
    const float* bv      = (const float*)d_in[12];
    const float* Wa      = (const float*)d_in[13];
    const float* ba      = (const float*)d_in[14];
    const float* ln_g    = (const float*)d_in[15];
    const float* ln_b    = (const float*)d_in[16];
    const float* rel_att = (const float*)d_in[17];
    const float* rel_msg = (const float*)d_in[18];
    const float* rel_pri = (const float*)d_in[19];
    const float* nta     = (const float*)d_in[20];
    const float* nta1    = (const float*)d_in[21];
    const float* skipp   = (const float*)d_in[22];
    const float* wgt     = (const float*)d_in[23];
    const float* afc_w   = (const float*)d_in[24];

    char* cur = (char*)d_ws;
    auto alloc = [&](size_t bytes) {
        char* p = cur;
        cur += (bytes + 63) & ~(size_t)63;
        return (void*)p;
    };
    ushort* xbf0  = (ushort*)alloc((size_t)NN * DD * 2);
    ushort* xbf1  = (ushort*)alloc((size_t)NN * DD * 2);
    ushort* kbf   = (ushort*)alloc((size_t)NN * DD * 2);
    ushort* qbf   = (ushort*)alloc((size_t)NN * DD * 2);
    ushort* vbf   = (ushort*)alloc((size_t)NN * DD * 2);
    float* tb     = (float*)alloc((size_t)NN * DD * 4);
    float* exbuf  = (float*)alloc((size_t)NE * HH * 4);
    float* den    = (float*)alloc((size_t)NN * RR * HH * 4);
    float* na_q   = (float*)alloc((size_t)NN * HH * 4);
    float* na_k   = (float*)alloc((size_t)NN * HH * 4);
    int*   cnt    = (int*)alloc((size_t)NN * 4);
    int*   rowptr = (int*)alloc((size_t)(NN + 1) * 4);
    int*   cursor = (int*)alloc((size_t)NN * 4);
    int*   perm   = (int*)alloc((size_t)NN * 4);
    int*   iperm  = (int*)alloc((size_t)NN * 4);
    int*   ptype  = (int*)alloc((size_t)NN * 4);
    unsigned* inm = (unsigned*)alloc((size_t)NN * 4);
    unsigned* outm= (unsigned*)alloc((size_t)NN * 4);
    int4*  edges  = (int4*)alloc((size_t)NE * 16);
    ushort* qr    = (ushort*)alloc((size_t)NN * RR * DD * 2);
    ushort* vr    = (ushort*)alloc((size_t)NN * RR * DD * 2);

    const int NODE_BLOCKS = NN / 4;            // 5000
    const int E_BLOCKS    = (NE + 255) / 256;  // 2344
    const int EH_BLOCKS   = (NE * HH) / 256;   // 9375
    const int RP_BLOCKS   = (RR * RP_CH) / 4;  // 1000
    const int KQV_BLOCKS  = NN / 16;           // 1250

    perm_scan_kernel<<<1, 1024, 0, stream>>>(ntype, perm, iperm, ptype);
    adapt_kernel<<<NODE_BLOCKS, 256, 0, stream>>>(h, ntype, iperm, adapt_W, adapt_b, xbf0);

    hipMemsetAsync(cnt, 0, (size_t)NN * 4, stream);
    hipMemsetAsync(inm, 0, (size_t)NN * 4, stream);
    hipMemsetAsync(outm, 0, (size_t)NN * 4, stream);
    csr_count_kernel<<<E_BLOCKS, 256, 0, stream>>>(dst, iperm, cnt);
    mask_build_kernel<<<E_BLOCKS, 256, 0, stream>>>(src, dst, etype, iperm, inm, outm);
    csr_scan_kernel<<<1, 1024, 0, stream>>>(cnt, rowptr, cursor);
    csr_fill_kernel<<<E_BLOCKS, 256, 0, stream>>>(src, dst, etype, iperm, cursor, edges);

    ushort* xin = xbf0;
    for (int l = 0; l < LL; ++l) {
        hipMemsetAsync(den, 0, (size_t)NN * RR * HH * 4, stream);

        kqv_mfma_kernel<<<KQV_BLOCKS, 256, 0, stream>>>(
            xin, ptype,
            Wk + (size_t)l * TT * DD * DD, bk + (size_t)l * TT * DD,
            Wq + (size_t)l * TT * DD * DD, bq + (size_t)l * TT * DD,
            Wv + (size_t)l * TT * DD * DD, bv + (size_t)l * TT * DD,
            afc_w + (size_t)l * 2 * DKK,
            kbf, qbf, vbf, na_q, na_k);

        relpreQV_kernel<<<RP_BLOCKS, 256, 0, stream>>>(
            qbf, vbf,
            rel_att + (size_t)l * RR * HH * 256, rel_msg + (size_t)l * RR * HH * 256,
            inm, outm, qr, vr);

        edge_logitsB_kernel<<<EH_BLOCKS, 256, 0, stream>>>(
            kbf, qr, edges,
            rel_pri + (size_t)l * RR * HH,
            nta + (size_t)l * TT, nta1 + (size_t)l * TT,
            na_q, na_k, wgt + l,
            exbuf, den);

        accum_csr_kernel<<<NODE_BLOCKS, 256, 0, stream>>>(
            vr, edges, rowptr, exbuf, den, tb);

        int last = (l == LL - 1) ? 1 : 0;
        ushort* xout = (xin == xbf0) ? xbf1 : xbf0;
        node_out_kernel<<<NODE_BLOCKS, 256, 0, stream>>>(
            xin, tb, den, ptype, perm,
            Wa + (size_t)l * TT * DD * DD, ba + (size_t)l * TT * DD,
            skipp + (size_t)l * TT,
            ln_g + (size_t)l * TT * DD, ln_b + (size_t)l * TT * DD,
            xout, (float*)d_out, last);
        xin = xout;
    }
}

// Round 16
// 737.362 us; speedup vs baseline: 1.0926x; 1.0926x over previous
//
#include <hip/hip_runtime.h>
#include <hip/hip_bf16.h>

#define NN 20000
#define NE 600000
#define DIN 128
#define DD 64
#define HH 4
#define DKK 16
#define LL 4
#define TT 3
#define RR 32
#define RP_TPW 10                 // tiles (16 nodes) per wave in relpreQV
#define RP_CH  125                // chunks per r: 125*10*16 = 20000

typedef __attribute__((ext_vector_type(8))) short bf16x8;
typedef __attribute__((ext_vector_type(4))) float f32x4;

__device__ __forceinline__ int src_nt(int e) { return e <= 9 ? 0 : (e <= 21 ? 1 : 2); }
__device__ __forceinline__ int dst_nt(int e) {
    if (e <= 2 || (e >= 10 && e <= 13) || (e >= 22 && e <= 24)) return 0;
    if ((e >= 3 && e <= 6) || (e >= 14 && e <= 17) || (e >= 25 && e <= 28)) return 1;
    return 2;
}
__device__ __forceinline__ float bf_lo(unsigned u) { return __uint_as_float(u << 16); }
__device__ __forceinline__ float bf_hi(unsigned u) { return __uint_as_float(u & 0xffff0000u); }
// round-to-nearest-even f32 -> bf16 bits
__device__ __forceinline__ ushort f2bf(float x) {
    unsigned u = __float_as_uint(x);
    return (ushort)((u + 0x7fffu + ((u >> 16) & 1u)) >> 16);
}

// ---- stable type-sort permutation: perm[slot]=orig, iperm[orig]=slot, ptype[slot] ----
__global__ void perm_scan_kernel(const int* __restrict__ ntype, int* __restrict__ perm,
                                 int* __restrict__ iperm, int* __restrict__ ptype) {
    __shared__ int wsum3[3][16];
    __shared__ int carry[3];
    __shared__ int offs[3];
    int tid = threadIdx.x;            // blockDim = 1024
    int lane = tid & 63, wid = tid >> 6;
    int loc[3] = {0, 0, 0};
    for (int i = tid; i < NN; i += 1024) loc[ntype[i]]++;
#pragma unroll
    for (int t = 0; t < 3; ++t) {
        int v = loc[t];
#pragma unroll
        for (int off = 1; off < 64; off <<= 1) v += __shfl_xor(v, off);
        if (lane == 0) wsum3[t][wid] = v;
    }
    __syncthreads();
    if (tid == 0) {
        int c0 = 0, c1 = 0;
        for (int i = 0; i < 16; ++i) { c0 += wsum3[0][i]; c1 += wsum3[1][i]; }
        offs[0] = 0; offs[1] = c0; offs[2] = c0 + c1;
        carry[0] = 0; carry[1] = 0; carry[2] = 0;
    }
    __syncthreads();
    for (int base = 0; base < NN; base += 1024) {
        int i = base + tid;
        int t = (i < NN) ? ntype[i] : -1;
        int exc[3];
#pragma unroll
        for (int tt = 0; tt < 3; ++tt) {
            int v = (t == tt) ? 1 : 0;
            int x = v;
#pragma unroll
            for (int off = 1; off < 64; off <<= 1) {
                int y = __shfl_up(x, off);
                if (lane >= off) x += y;
            }
            if (lane == 63) wsum3[tt][wid] = x;
            exc[tt] = x - v;
        }
        __syncthreads();
        if (wid == 0 && lane < 16) {
#pragma unroll
            for (int tt = 0; tt < 3; ++tt) {
                int w = wsum3[tt][lane];
#pragma unroll
                for (int off = 1; off < 16; off <<= 1) {
                    int y = __shfl_up(w, off);
                    if (lane >= off) w += y;
                }
                wsum3[tt][lane] = w;
            }
        }
        __syncthreads();
        if (i < NN) {
            int woff = (wid > 0) ? wsum3[t][wid - 1] : 0;
            int slot = offs[t] + carry[t] + woff + exc[t];
            perm[slot] = i; iperm[i] = slot; ptype[slot] = t;
        }
        __syncthreads();
        if (tid == 0) { for (int tt = 0; tt < 3; ++tt) carry[tt] += wsum3[tt][15]; }
        __syncthreads();
    }
}

// ---- x = tanh(h @ adapt_W[ntype] + adapt_b[ntype]); bf16 out, permuted ----
__global__ void adapt_kernel(const float* __restrict__ h, const int* __restrict__ ntype,
                             const int* __restrict__ iperm,
                             const float* __restrict__ W, const float* __restrict__ b,
                             ushort* __restrict__ xbf) {
    int wid = (blockIdx.x * blockDim.x + threadIdx.x) >> 6;
    int lane = threadIdx.x & 63;
    if (wid >= NN) return;
    int t = ntype[wid];
    const float* Wt = W + (size_t)t * DIN * DD;
    float h0 = h[(size_t)wid * DIN + lane];
    float h1 = h[(size_t)wid * DIN + 64 + lane];
    float acc = b[t * DD + lane];
#pragma unroll
    for (int d = 0; d < 64; ++d) acc += __shfl(h0, d) * Wt[d * DD + lane];
#pragma unroll
    for (int d = 0; d < 64; ++d) acc += __shfl(h1, d) * Wt[(64 + d) * DD + lane];
    xbf[(size_t)iperm[wid] * DD + lane] = f2bf(tanhf(acc));
}

// ---- CSR build over PERMUTED dst; fill writes ONE packed int4 per edge ----
__global__ void csr_count_kernel(const int* __restrict__ dst, const int* __restrict__ iperm,
                                 int* __restrict__ cnt) {
    int e = blockIdx.x * blockDim.x + threadIdx.x;
    if (e < NE) atomicAdd(&cnt[iperm[dst[e]]], 1);
}

__global__ void csr_scan_kernel(const int* __restrict__ cnt, int* __restrict__ rowptr,
                                int* __restrict__ cursor) {
    __shared__ int wsuml[16];
    __shared__ int s_carry;
    int tid = threadIdx.x;            // blockDim = 1024
    int lane = tid & 63, wid = tid >> 6;
    if (tid == 0) s_carry = 0;
    __syncthreads();
    for (int base = 0; base < NN; base += 1024) {
        int i = base + tid;
        int v = (i < NN) ? cnt[i] : 0;
        int x = v;
#pragma unroll
        for (int off = 1; off < 64; off <<= 1) {
            int y = __shfl_up(x, off);
            if (lane >= off) x += y;
        }
        if (lane == 63) wsuml[wid] = x;
        __syncthreads();
        if (wid == 0 && lane < 16) {
            int w = wsuml[lane];
#pragma unroll
            for (int off = 1; off < 16; off <<= 1) {
                int y = __shfl_up(w, off);
                if (lane >= off) w += y;
            }
            wsuml[lane] = w;
        }
        __syncthreads();
        int woff = (wid > 0) ? wsuml[wid - 1] : 0;
        int carry = s_carry;
        int excl = carry + woff + x - v;
        if (i < NN) { rowptr[i] = excl; cursor[i] = excl; }
        __syncthreads();
        if (tid == 1023) s_carry = carry + wsuml[15];
        __syncthreads();
    }
    if (tid == 0) rowptr[NN] = NE;
}

__global__ void csr_fill_kernel(const int* __restrict__ src, const int* __restrict__ dst,
                                const int* __restrict__ et, const int* __restrict__ iperm,
                                int* __restrict__ cursor, int4* __restrict__ edges) {
    int e = blockIdx.x * blockDim.x + threadIdx.x;
    if (e >= NE) return;
    int d = iperm[dst[e]];
    int p = atomicAdd(&cursor[d], 1);
    edges[p] = make_int4(iperm[src[e]], d, et[e], 0);
}

// ---- kqv via MFMA over type-sorted nodes; block = 16 nodes, wave = head o-tile ----
__global__ __launch_bounds__(256) void kqv_mfma_kernel(
        const ushort* __restrict__ xbf, const int* __restrict__ ptype,
        const float* __restrict__ Wk, const float* __restrict__ bk,
        const float* __restrict__ Wq, const float* __restrict__ bq,
        const float* __restrict__ Wv, const float* __restrict__ bv,
        const float* __restrict__ afc,
        ushort* __restrict__ kbf, ushort* __restrict__ qbf, ushort* __restrict__ vbf,
        float* __restrict__ na_q, float* __restrict__ na_k) {
    int p0 = blockIdx.x * 16;
    int lane = threadIdx.x & 63;
    int w = threadIdx.x >> 6;       // head / o-tile
    int m = lane & 15, g = lane >> 4;
    int k0 = g * 8, frow = g * 4, ob = w * 16;
    int myn = p0 + m;
    int myt = ptype[myn];
    int t0 = ptype[p0], t1 = ptype[p0 + 15];
    bf16x8 b0 = *(const bf16x8*)(xbf + (size_t)myn * DD + k0);
    bf16x8 b1 = *(const bf16x8*)(xbf + (size_t)myn * DD + 32 + k0);
    for (int t = t0; t <= t1; ++t) {
        const float* WkT = Wk + (size_t)t * DD * DD; const float* bkT = bk + t * DD;
        const float* WqT = Wq + (size_t)t * DD * DD; const float* bqT = bq + t * DD;
        const float* WvT = Wv + (size_t)t * DD * DD; const float* bvT = bv + t * DD;
        bf16x8 ak0, ak1, aq0, aq1, av0, av1;
        int col = ob + m;
#pragma unroll
        for (int j = 0; j < 8; ++j) {
            ak0[j] = (short)f2bf(WkT[(k0 + j) * DD + col]);
            ak1[j] = (short)f2bf(WkT[(32 + k0 + j) * DD + col]);
            aq0[j] = (short)f2bf(WqT[(k0 + j) * DD + col]);
            aq1[j] = (short)f2bf(WqT[(32 + k0 + j) * DD + col]);
            av0[j] = (short)f2bf(WvT[(k0 + j) * DD + col]);
            av1[j] = (short)f2bf(WvT[(32 + k0 + j) * DD + col]);
        }
        f32x4 z = {0.f, 0.f, 0.f, 0.f};
        f32x4 ck = __builtin_amdgcn_mfma_f32_16x16x32_bf16(ak0, b0, z, 0, 0, 0);
        ck = __builtin_amdgcn_mfma_f32_16x16x32_bf16(ak1, b1, ck, 0, 0, 0);
        f32x4 cq = __builtin_amdgcn_mfma_f32_16x16x32_bf16(aq0, b0, z, 0, 0, 0);
        cq = __builtin_amdgcn_mfma_f32_16x16x32_bf16(aq1, b1, cq, 0, 0, 0);
        f32x4 cv = __builtin_amdgcn_mfma_f32_16x16x32_bf16(av0, b0, z, 0, 0, 0);
        cv = __builtin_amdgcn_mfma_f32_16x16x32_bf16(av1, b1, cv, 0, 0, 0);
        float sq = 0.f, sk = 0.f;
        ushort4 okk, oqq, ovv;
#pragma unroll
        for (int j = 0; j < 4; ++j) {
            int o = ob + frow + j;
            float kk = ck[j] + bkT[o];
            float qq = cq[j] + bqT[o];
            float vv = cv[j] + bvT[o];
            sq += qq * afc[frow + j];
            sk += kk * afc[16 + frow + j];
            ((ushort*)&okk)[j] = f2bf(kk);
            ((ushort*)&oqq)[j] = f2bf(qq);
            ((ushort*)&ovv)[j] = f2bf(vv);
        }
        sq += __shfl_xor(sq, 16); sq += __shfl_xor(sq, 32);
        sk += __shfl_xor(sk, 16); sk += __shfl_xor(sk, 32);
        if (myt == t) {
            size_t ob8 = (size_t)myn * DD + ob + frow;
            *(ushort4*)(kbf + ob8) = okk;
            *(ushort4*)(qbf + ob8) = oqq;
            *(ushort4*)(vbf + ob8) = ovv;
            if (g == 0) {
                na_q[myn * HH + w] = sq;
                na_k[myn * HH + w] = sk;
            }
        }
    }
}

// ---- relpre QV: qr[n,r] = A_r q[n], vr[n,r] = M_r^T v[n]. MFMA + swizzled LDS ----
__global__ __launch_bounds__(256) void relpreQV_kernel(
        const ushort* __restrict__ qbf, const ushort* __restrict__ vbf,
        const float* __restrict__ relA, const float* __restrict__ relM,
        ushort* __restrict__ qr, ushort* __restrict__ vr) {
    __shared__ __align__(16) ushort lds[4][2][16 * DD];   // [wave][Q/V][16 rows x 128B]
    int gw = (blockIdx.x * blockDim.x + threadIdx.x) >> 6;
    int lane = threadIdx.x & 63;
    int wv = threadIdx.x >> 6;
    int r = gw / RP_CH;
    int c = gw % RP_CH;
    int m = lane & 15;
    int g = lane >> 4;
    int k0 = g * 8;
    bf16x8 aQ[HH], aV[HH];
#pragma unroll
    for (int h = 0; h < HH; ++h) {
        bf16x8 zq = {0, 0, 0, 0, 0, 0, 0, 0};
        bf16x8 zv = {0, 0, 0, 0, 0, 0, 0, 0};
        if (k0 < 16) {
            const float* Ab = relA + (size_t)(r * HH + h) * 256;
            const float* Mb = relM + (size_t)(r * HH + h) * 256;
#pragma unroll
            for (int j = 0; j < 8; ++j) {
                zq[j] = (short)f2bf(Ab[m * 16 + k0 + j]);
                zv[j] = (short)f2bf(Mb[(k0 + j) * 16 + m]);
            }
        }
        aQ[h] = zq; aV[h] = zv;
    }
    int ksafe = k0 & 8;
    int nd = lane >> 3;           // store phase: node sub-index 0..7
    int ch = lane & 7;            // 16B chunk within node row
    int wswz = (m & 7) << 1;      // write-side chunk XOR
    for (int t = 0; t < RP_TPW; ++t) {
        int n0 = (c * RP_TPW + t) * 16;
#pragma unroll
        for (int h = 0; h < HH; ++h) {
            size_t brow = (size_t)(n0 + m) * DD + h * 16 + ksafe;
            bf16x8 bQ = *(const bf16x8*)(qbf + brow);
            bf16x8 bV = *(const bf16x8*)(vbf + brow);
            f32x4 z = {0.f, 0.f, 0.f, 0.f};
            f32x4 cq = __builtin_amdgcn_mfma_f32_16x16x32_bf16(aQ[h], bQ, z, 0, 0, 0);
            f32x4 cv = __builtin_amdgcn_mfma_f32_16x16x32_bf16(aV[h], bV, z, 0, 0, 0);
            ushort4 oq, ov;
            oq.x = f2bf(cq[0]); oq.y = f2bf(cq[1]); oq.z = f2bf(cq[2]); oq.w = f2bf(cq[3]);
            ov.x = f2bf(cv[0]); ov.y = f2bf(cv[1]); ov.z = f2bf(cv[2]); ov.w = f2bf(cv[3]);
            int cidx = (h * 4 + g) ^ wswz;         // swizzled 8B-chunk index
            int li = m * DD + cidx * 4;
            *(ushort4*)&lds[wv][0][li] = oq;
            *(ushort4*)&lds[wv][1][li] = ov;
        }
        asm volatile("s_waitcnt lgkmcnt(0)" ::: "memory");
#pragma unroll
        for (int p = 0; p < 2; ++p) {
            int node = p * 8 + nd;
            int c0 = (ch * 2) ^ ((node & 7) << 1); // same XOR on read side
            int li = node * DD + c0 * 4;
            uint4 dq = *(const uint4*)&lds[wv][0][li];
            uint4 dv = *(const uint4*)&lds[wv][1][li];
            size_t gb = ((size_t)(n0 + node) * RR + r) * DD + ch * 8;
            *(uint4*)(qr + gb) = dq;
            *(uint4*)(vr + gb) = dv;
        }
        asm volatile("s_waitcnt lgkmcnt(0)" ::: "memory");
    }
}

// ---- edge pass: thread per (sorted-j, h); packed edge load ----
__global__ void edge_logitsB_kernel(const ushort* __restrict__ kbf,
                                    const ushort* __restrict__ qr,
                                    const int4* __restrict__ edges,
                                    const float* __restrict__ pri,
                                    const float* __restrict__ nta, const float* __restrict__ nta1,
                                    const float* __restrict__ na_q, const float* __restrict__ na_k,
                                    const float* __restrict__ wgt,
                                    float* __restrict__ ex_out, float* __restrict__ den) {
    int idx = blockIdx.x * blockDim.x + threadIdx.x;
    if (idx >= NE * HH) return;
    int j = idx >> 2, hh = idx & 3;
    int4 ed = edges[j];
    int s = ed.x, dd = ed.y, r = ed.z;
    const uint4* qp = (const uint4*)(qr + ((size_t)dd * RR + r) * DD + hh * 16);
    uint4 a0 = qp[0], a1 = qp[1];
    const uint4* kp = (const uint4*)(kbf + (size_t)s * DD + hh * 16);
    uint4 b0 = kp[0], b1 = kp[1];
    float att = bf_lo(a0.x) * bf_lo(b0.x) + bf_hi(a0.x) * bf_hi(b0.x)
              + bf_lo(a0.y) * bf_lo(b0.y) + bf_hi(a0.y) * bf_hi(b0.y)
              + bf_lo(a0.z) * bf_lo(b0.z) + bf_hi(a0.z) * bf_hi(b0.z)
              + bf_lo(a0.w) * bf_lo(b0.w) + bf_hi(a0.w) * bf_hi(b0.w)
              + bf_lo(a1.x) * bf_lo(b1.x) + bf_hi(a1.x) * bf_hi(b1.x)
              + bf_lo(a1.y) * bf_lo(b1.y) + bf_hi(a1.y) * bf_hi(b1.y)
              + bf_lo(a1.z) * bf_lo(b1.z) + bf_hi(a1.z) * bf_hi(b1.z)
              + bf_lo(a1.w) * bf_lo(b1.w) + bf_hi(a1.w) * bf_hi(b1.w);
    att = att * pri[r * HH + hh] * 0.25f;
    float c = nta1[dst_nt(r)] * na_q[dd * HH + hh] + nta[src_nt(r)] * na_k[s * HH + hh];
    float na = c > 0.f ? c : 0.01f * c;
    float sw = 1.f / (1.f + expf(-wgt[0]));
    float exv = expf(att + sw * na);
    ex_out[idx] = exv;
    atomicAdd(&den[((size_t)dd * RR + r) * HH + hh], exv);
}

// ---- accumulation: wave per dst; 4x-unrolled; packed edge loads ----
__global__ void accum_csr_kernel(const ushort* __restrict__ vr,
                                 const int4* __restrict__ edges,
                                 const int* __restrict__ rowptr,
                                 const float* __restrict__ ex, const float* __restrict__ den,
                                 float* __restrict__ tacc) {
    int n = (blockIdx.x * blockDim.x + threadIdx.x) >> 6;
    int lane = threadIdx.x & 63;
    if (n >= NN) return;
    int beg = rowptr[n], end = rowptr[n + 1];
    int hh = lane >> 4;
    const float* denrow = den + (size_t)n * RR * HH + hh;
    float acc = 0.f;
    int j = beg;
    for (; j + 3 < end; j += 4) {
        int4 e0i = edges[j], e1i = edges[j + 1], e2i = edges[j + 2], e3i = edges[j + 3];
        float v0 = bf_lo((unsigned)vr[((size_t)e0i.x * RR + e0i.z) * DD + lane]);
        float v1 = bf_lo((unsigned)vr[((size_t)e1i.x * RR + e1i.z) * DD + lane]);
        float v2 = bf_lo((unsigned)vr[((size_t)e2i.x * RR + e2i.z) * DD + lane]);
        float v3 = bf_lo((unsigned)vr[((size_t)e3i.x * RR + e3i.z) * DD + lane]);
        float e0 = ex[(size_t)(j)     * HH + hh];
        float e1 = ex[(size_t)(j + 1) * HH + hh];
        float e2 = ex[(size_t)(j + 2) * HH + hh];
        float e3 = ex[(size_t)(j + 3) * HH + hh];
        float d0 = denrow[e0i.z * HH];
        float d1 = denrow[e1i.z * HH];
        float d2 = denrow[e2i.z * HH];
        float d3 = denrow[e3i.z * HH];
        acc += e0 * __builtin_amdgcn_rcpf(d0) * v0;
        acc += e1 * __builtin_amdgcn_rcpf(d1) * v1;
        acc += e2 * __builtin_amdgcn_rcpf(d2) * v2;
        acc += e3 * __builtin_amdgcn_rcpf(d3) * v3;
    }
    for (; j < end; ++j) {
        int4 ei = edges[j];
        float val = bf_lo((unsigned)vr[((size_t)ei.x * RR + ei.z) * DD + lane]);
        float p = ex[(size_t)j * HH + hh] * __builtin_amdgcn_rcpf(denrow[ei.z * HH]);
        acc += p * val;
    }
    tacc[(size_t)n * DD + lane] = acc;
}

// ---- node finalize (permuted space; last layer un-permutes to d_out) ----
__global__ void node_out_kernel(const ushort* __restrict__ xbf_in, const float* __restrict__ tacc,
                                const float* __restrict__ den, const int* __restrict__ ptype,
                                const int* __restrict__ perm,
                                const float* __restrict__ Wa, const float* __restrict__ ba,
                                const float* __restrict__ skipp,
                                const float* __restrict__ ln_g, const float* __restrict__ ln_b,
                                ushort* __restrict__ xbf_out, float* __restrict__ fout, int last) {
    int n = (blockIdx.x * blockDim.x + threadIdx.x) >> 6;
    int lane = threadIdx.x & 63;
    if (n >= NN) return;
    int t = ptype[n];
    int pres = 0;
    if (lane < RR) pres = (den[((size_t)n * RR + lane) * HH] > 0.f) ? 1 : 0;
    unsigned long long mask = __ballot(pres != 0);
    float cnt = (float)__popcll(mask);
    float divisor = fmaxf(cnt, 1.0f);
    float tv = tacc[(size_t)n * DD + lane] / divisor;
    const float* Wt = Wa + (size_t)t * DD * DD;
    float acc = ba[t * DD + lane];
#pragma unroll
    for (int d = 0; d < 64; ++d) acc += __shfl(tv, d) * Wt[d * DD + lane];
    float alpha = 1.f / (1.f + expf(-skipp[t]));
    float xi = bf_lo((unsigned)xbf_in[(size_t)n * DD + lane]);
    float out = acc * alpha + xi * (1.f - alpha);
    float s = out;
#pragma unroll
    for (int off = 1; off < 64; off <<= 1) s += __shfl_xor(s, off);
    float mu = s * (1.f / 64.f);
    float d0 = out - mu;
    float s2 = d0 * d0;
#pragma unroll
    for (int off = 1; off < 64; off <<= 1) s2 += __shfl_xor(s2, off);
    float var = s2 * (1.f / 64.f);
    float xn = d0 * rsqrtf(var + 1e-5f);
    float res = xn * ln_g[t * DD + lane] + ln_b[t * DD + lane];
    if (last) fout[(size_t)perm[n] * DD + lane] = res;
    else      xbf_out[(size_t)n * DD + lane] = f2bf(res);
}

extern "C" void kernel_launch(void* const* d_in, const int* in_sizes, int n_in,
                              void* d_out, int out_size, void* d_ws, size_t ws_size,
                              hipStream_t stream) {
    const float* h       = (const float*)d_in[0];
    const int*   src     = (const int*)d_in[1];
    const int*   dst     = (const int*)d_in[2];
    const int*   etype   = (const int*)d_in[3];
    const int*   ntype   = (const int*)d_in[4];
    const float* adapt_W = (const float*)d_in[5];
    const float* adapt_b = (const float*)d_in[6];
    const float* Wk      = (const float*)d_in[7];
    const float* bk      = (const float*)d_in[8];
    const float* Wq      = (const float*)d_in[9];
    const float* bq      = (const float*)d_in[10];
    const float* Wv      = (const float*)d_in[11];
    const float* bv      = (const float*)d_in[12];
    const float* Wa      = (const float*)d_in[13];
    const float* ba      = (const float*)d_in[14];
    const float* ln_g    = (const float*)d_in[15];
    const float* ln_b    = (const float*)d_in[16];
    const float* rel_att = (const float*)d_in[17];
    const float* rel_msg = (const float*)d_in[18];
    const float* rel_pri = (const float*)d_in[19];
    const float* nta     = (const float*)d_in[20];
    const float* nta1    = (const float*)d_in[21];
    const float* skipp   = (const float*)d_in[22];
    const float* wgt     = (const float*)d_in[23];
    const float* afc_w   = (const float*)d_in[24];

    char* cur = (char*)d_ws;
    auto alloc = [&](size_t bytes) {
        char* p = cur;
        cur += (bytes + 63) & ~(size_t)63;
        return (void*)p;
    };
    ushort* xbf0  = (ushort*)alloc((size_t)NN * DD * 2);
    ushort* xbf1  = (ushort*)alloc((size_t)NN * DD * 2);
    ushort* kbf   = (ushort*)alloc((size_t)NN * DD * 2);
    ushort* qbf   = (ushort*)alloc((size_t)NN * DD * 2);
    ushort* vbf   = (ushort*)alloc((size_t)NN * DD * 2);
    float* tb     = (float*)alloc((size_t)NN * DD * 4);
    float* exbuf  = (float*)alloc((size_t)NE * HH * 4);
    float* den    = (float*)alloc((size_t)NN * RR * HH * 4);
    float* na_q   = (float*)alloc((size_t)NN * HH * 4);
    float* na_k   = (float*)alloc((size_t)NN * HH * 4);
    int*   cnt    = (int*)alloc((size_t)NN * 4);
    int*   rowptr = (int*)alloc((size_t)(NN + 1) * 4);
    int*   cursor = (int*)alloc((size_t)NN * 4);
    int*   perm   = (int*)alloc((size_t)NN * 4);
    int*   iperm  = (int*)alloc((size_t)NN * 4);
    int*   ptype  = (int*)alloc((size_t)NN * 4);
    int4*  edges  = (int4*)alloc((size_t)NE * 16);
    ushort* qr    = (ushort*)alloc((size_t)NN * RR * DD * 2);
    ushort* vr    = (ushort*)alloc((size_t)NN * RR * DD * 2);

    const int NODE_BLOCKS = NN / 4;            // 5000
    const int E_BLOCKS    = (NE + 255) / 256;  // 2344
    const int EH_BLOCKS   = (NE * HH) / 256;   // 9375
    const int RP_BLOCKS   = (RR * RP_CH) / 4;  // 1000
    const int KQV_BLOCKS  = NN / 16;           // 1250

    perm_scan_kernel<<<1, 1024, 0, stream>>>(ntype, perm, iperm, ptype);
    adapt_kernel<<<NODE_BLOCKS, 256, 0, stream>>>(h, ntype, iperm, adapt_W, adapt_b, xbf0);

    hipMemsetAsync(cnt, 0, (size_t)NN * 4, stream);
    csr_count_kernel<<<E_BLOCKS, 256, 0, stream>>>(dst, iperm, cnt);
    csr_scan_kernel<<<1, 1024, 0, stream>>>(cnt, rowptr, cursor);
    csr_fill_kernel<<<E_BLOCKS, 256, 0, stream>>>(src, dst, etype, iperm, cursor, edges);

    ushort* xin = xbf0;
    for (int l = 0; l < LL; ++l) {
        hipMemsetAsync(den, 0, (size_t)NN * RR * HH * 4, stream);

        kqv_mfma_kernel<<<KQV_BLOCKS, 256, 0, stream>>>(
            xin, ptype,
            Wk + (size_t)l * TT * DD * DD, bk + (size_t)l * TT * DD,
            Wq + (size_t)l * TT * DD * DD, bq + (size_t)l * TT * DD,
            Wv + (size_t)l * TT * DD * DD, bv + (size_t)l * TT * DD,
            afc_w + (size_t)l * 2 * DKK,
            kbf, qbf, vbf, na_q, na_k);

        relpreQV_kernel<<<RP_BLOCKS, 256, 0, stream>>>(
            qbf, vbf,
            rel_att + (size_t)l * RR * HH * 256, rel_msg + (size_t)l * RR * HH * 256,
            qr, vr);

        edge_logitsB_kernel<<<EH_BLOCKS, 256, 0, stream>>>(
            kbf, qr, edges,
            rel_pri + (size_t)l * RR * HH,
            nta + (size_t)l * TT, nta1 + (size_t)l * TT,
            na_q, na_k, wgt + l,
            exbuf, den);

        accum_csr_kernel<<<NODE_BLOCKS, 256, 0, stream>>>(
            vr, edges, rowptr, exbuf, den, tb);

        int last = (l == LL - 1) ? 1 : 0;
        ushort* xout = (xin == xbf0) ? xbf1 : xbf0;
        node_out_kernel<<<NODE_BLOCKS, 256, 0, stream>>>(
            xin, tb, den, ptype, perm,
            Wa + (size_t)l * TT * DD * DD, ba + (size_t)l * TT * DD,
            skipp + (size_t)l * TT,
            ln_g + (size_t)l * TT * DD, ln_b + (size_t)l * TT * DD,
            xout, (float*)d_out, last);
        xin = xout;
    }
}